// Round 12
// baseline (180.784 us; speedup 1.0000x reference)
//
#include <hip/hip_runtime.h>
#include <math.h>

#define HW 2304           // 48*48
#define O192 192
#define SCALE_F 0.35355339059327373f   // 8^-0.5

typedef unsigned int u32;
typedef __attribute__((address_space(1))) const u32 gu32;
typedef __attribute__((address_space(3))) u32 lu32;
// async global->LDS DMA, 16B per lane; LDS dest = wave-uniform base + lane*16
__device__ __forceinline__ void dma16(const void* g, void* l) {
  __builtin_amdgcn_global_load_lds((gu32*)g, (lu32*)l, 16, 0, 0);
}

// ------------- Kernel F: fused front end (qkv + conv, role-split) -----------
// conv no longer reads QKV: conv(Wqkv*F) == conv_Weff(F) with
// W_eff[o,c',ky,kx] = sum_ci wg[o,ci,ky,kx] * Wqkv[T*64+ci, c'] (linearity;
// zero-pad commutes pre-GELU). So conv-role blocks depend only on inputs and
// run CONCURRENTLY with qkv-role blocks in one kernel: one launch+gap saved.
// Blocks 0..127: conv-role, one (T,o) each: build W_eff in LDS (2 passes of
// 32 ci to keep LDS at 39KB -> 4 blocks/CU for qkv-role), then the original
// conv body over all (b,oy) reading F. Blocks 128..1279: original qkv code.
__global__ __launch_bounds__(256) void front_kernel(
    const float* __restrict__ F, const float* __restrict__ Wqkv,
    const float* __restrict__ Wq, const float* __restrict__ Bq,
    const float* __restrict__ Wk, const float* __restrict__ Bk,
    float* __restrict__ QKV, float* __restrict__ V2, float* __restrict__ QD) {
  __shared__ __align__(16) float sS[9792]; // conv: [0,2048) Wqkv-half then sRed; [2048,9792) W_eff
                                           // qkv: [0,384) weight tiles
  int blk = blockIdx.x;
  int tid = threadIdx.x;
  if (blk < 128) {
    // ================= conv role: (T, o) =================
    int T = blk >> 6, o = blk & 63;
    const float* Wg = (T ? Wk : Wq) + o * 7744;
    float* sWq = sS;           // 2048 f: 32 ci x 64 cp (per half)
    float* sWe = sS + 2048;    // 7744 f: W_eff [c'][121]
    for (int half = 0; half < 2; half++) {
      for (int i = tid; i < 2048; i += 256)
        sWq[i] = Wqkv[(T * 64 + half * 32 + (i >> 6)) * 64 + (i & 63)];
      __syncthreads();
      for (int j = tid; j < 7744; j += 256) {
        int cp = j / 121, t1 = j - cp * 121;
        float s = (half == 0) ? 0.f : sWe[j];
        #pragma unroll
        for (int ci = 0; ci < 32; ci++)
          s = fmaf(Wg[(half * 32 + ci) * 121 + t1], sWq[ci * 64 + cp], s);
        sWe[j] = s;
      }
      __syncthreads();
    }
    // conv body (original structure), input = F, weights = W_eff
    int wv = tid >> 6, c = tid & 63;
    float bias = T ? Bk[o] : Bq[o];
    float* sRed = sS;          // 1536 f in the dead Wqkv region
    for (int bi = 0; bi < 2; bi++) {
      const float* base = F + (bi * 64 + c) * HW;
      for (int oy = 0; oy < 6; oy++) {
        float acc[6];
        #pragma unroll
        for (int ox = 0; ox < 6; ox++) acc[ox] = 0.f;
        for (int kyi = 0; kyi < 3; kyi++) {
          int ky = wv * 3 + kyi;
          if (ky > 10) break;
          int y = oy * 8 - 2 + ky;
          if ((unsigned)y < 48u) {
            float xrow[48];
            #pragma unroll
            for (int x = 0; x < 48; x++) xrow[x] = base[y * 48 + x];
            #pragma unroll
            for (int kx = 0; kx < 11; kx++) {
              float wt = sWe[c * 121 + ky * 11 + kx];
              #pragma unroll
              for (int ox = 0; ox < 6; ox++) {
                int x = ox * 8 - 2 + kx;
                if (x >= 0 && x < 48) acc[ox] = fmaf(xrow[x], wt, acc[ox]);
              }
            }
          }
        }
        __syncthreads();   // sRed reuse safe (also first time: after W_eff)
        #pragma unroll
        for (int ox = 0; ox < 6; ox++) sRed[(wv * 64 + c) * 6 + ox] = acc[ox];
        __syncthreads();
        if (tid < 64) {
          float r[6];
          #pragma unroll
          for (int ox = 0; ox < 6; ox++)
            r[ox] = sRed[tid * 6 + ox] + sRed[(64 + tid) * 6 + ox]
                  + sRed[(128 + tid) * 6 + ox] + sRed[(192 + tid) * 6 + ox];
          #pragma unroll
          for (int off = 32; off; off >>= 1) {
            #pragma unroll
            for (int ox = 0; ox < 6; ox++) r[ox] += __shfl_down(r[ox], off, 64);
          }
          if (tid == 0) {
            #pragma unroll
            for (int ox = 0; ox < 6; ox++) {
              float g = r[ox] + bias;
              QD[((T * 2 + bi) * 64 + o) * 36 + oy * 6 + ox] =
                0.5f * g * (1.0f + erff(g * 0.70710678118654752f));
            }
          }
        }
      }
    }
  } else {
    // ================= qkv role (original) =================
    int qb = blk - 128;
    float* sW = sS;
    int idx0 = qb * 256;
    int r0 = idx0 / HW;
    int r1 = (idx0 + 255) / HW;
    if (tid < 192) {
      int g = tid >> 6, c = tid & 63;
      sW[tid]       = Wqkv[((r0 & 63) + g * 64) * 64 + c];
      sW[192 + tid] = Wqkv[((r1 & 63) + g * 64) * 64 + c];
    }
    __syncthreads();
    int idx = idx0 + tid;
    int p  = idx % HW;
    int r  = idx / HW;
    int o0 = r & 63;
    int b  = r >> 6;
    const float4* w4 = (const float4*)(sW + ((r == r0) ? 0 : 192));
    const float* f = F + (b * 64) * HW + p;
    float aq = 0.f, ak = 0.f, av = 0.f;
    #pragma unroll 4
    for (int c4 = 0; c4 < 16; c4++) {
      float4 wq = w4[c4];
      float4 wk = w4[16 + c4];
      float4 wv = w4[32 + c4];
      float f0 = f[(c4 * 4 + 0) * HW];
      float f1 = f[(c4 * 4 + 1) * HW];
      float f2 = f[(c4 * 4 + 2) * HW];
      float f3 = f[(c4 * 4 + 3) * HW];
      aq = fmaf(wq.x, f0, aq); ak = fmaf(wk.x, f0, ak); av = fmaf(wv.x, f0, av);
      aq = fmaf(wq.y, f1, aq); ak = fmaf(wk.y, f1, ak); av = fmaf(wv.y, f1, av);
      aq = fmaf(wq.z, f2, aq); ak = fmaf(wk.z, f2, ak); av = fmaf(wv.z, f2, av);
      aq = fmaf(wq.w, f3, aq); ak = fmaf(wk.w, f3, ak); av = fmaf(wv.w, f3, av);
    }
    float* qp = QKV + (b * HW + p) * O192;
    qp[o0]      = aq;
    qp[o0 + 64] = ak;
    V2[(((b << 3) + (o0 >> 3)) * HW + p) * 8 + (o0 & 7)] = av;
  }
}

// ---------------- Kernel C: attention (r9, best measured: 132.45) -----------
// Lessons: no device fences (r1); V LDS-staged via dma16 (r4); no VGPR cap
// (r2/r5/r6 spill); unroll-1 pins VGPR at 44 (r8: appetite -> 208 VGPR).
// r7/r9/r10/r11 all ~41us: attn is at its structural floor for this
// decomposition -- frozen at the r9 configuration.
#define OFF_V   0        // 4608 f : V quarter [12jy][48jx][8c]
#define OFF_EA  4608     // 384  f : eA2 [jyL][r16][2] (row r16, row r16+16)
#define OFF_PHT 4992     // 384  f : PH^T [jy][c]
#define OFF_PWT 5376     // 384  f : PW^T [jx][c]
#define OFF_E   5760     // 36+4 f : E [J]
#define OFF_QT  5800     // 256  f : sQT [c][row]  (transposed)
#define OFF_R   6056     // 1152 f : sRed [4w][2k][16 r16][9]
#define SBUF_N  7208     // 28832 B -> 5 blocks/CU

__global__ __launch_bounds__(256) void attn_kernel(
    const float* __restrict__ QKV, const float* __restrict__ V2,
    const float* __restrict__ QD, const float* __restrict__ PH,
    const float* __restrict__ PW, float* __restrict__ out) {
  __shared__ __align__(16) float sB[SBUF_N];
  int blk = blockIdx.x;
  int bh = blk / 72;
  int S  = blk - bh * 72;         // 32-row supertile; I column = S>>1
  int b = bh >> 3, h = bh & 7;
  int tid = threadIdx.x;
  int w = tid >> 6, lane = tid & 63;   // 4 waves
  int rl16 = lane & 15;                // first owned row; second is rl16+16
  int g  = w * 4 + (lane >> 4);        // jx-group in [0,16), 3 jx each
  for (int t = tid; t < 384; t += 256) {
    sB[OFF_PHT + t] = PH[(t & 7) * 48 + (t >> 3)];
    sB[OFF_PWT + t] = PW[(t & 7) * 48 + (t >> 3)];
  }
  if (tid < 36) {   // fused dots: E[J] = exp(SCALE * qd[:,I].kd[:,J])
    int I = S >> 1;
    float acc = 0.f;
    #pragma unroll
    for (int c8 = 0; c8 < 8; c8++) {
      float qv = QD[((0 + b) * 64 + h * 8 + c8) * 36 + I];
      float kv = QD[((2 + b) * 64 + h * 8 + c8) * 36 + tid];
      acc = fmaf(qv, kv, acc);
    }
    sB[OFF_E + tid] = __expf(SCALE_F * acc);
  }
  {  // sQT[c][row] transposed: 256 threads = 32 rows x 8 c
    int row = tid >> 3, c = tid & 7;
    sB[OFF_QT + c * 32 + row] =
      QKV[(b * HW + S * 32 + row) * O192 + h * 8 + c];
  }
  { // V quarter 0 via DMA: 18 chunks x 1 KiB over 4 waves
    const char* src = (const char*)(V2 + (size_t)bh * (HW * 8));
    for (int m = w; m < 18; m += 4)
      dma16(src + m * 1024 + lane * 16, (char*)(sB + OFF_V) + m * 1024);
  }
  __syncthreads();   // publish tables/QT; drains V(0) DMA
  float eB[2][3];
  #pragma unroll
  for (int k = 0; k < 2; k++) {
    int row = rl16 + k * 16;
    #pragma unroll
    for (int i = 0; i < 3; i++) {
      const float* pp = sB + OFF_PWT + (g * 3 + i) * 8;
      float d = 0.f;
      #pragma unroll
      for (int j = 0; j < 8; j++) d = fmaf(sB[OFF_QT + j * 32 + row], pp[j], d);
      eB[k][i] = __expf(d);
    }
  }
  float acc0[9], acc1[9];
  #pragma unroll
  for (int c = 0; c < 9; c++) { acc0[c] = 0.f; acc1[c] = 0.f; }
  const float4* sV4 = (const float4*)(sB + OFF_V);
  #pragma unroll 1
  for (int q = 0; q < 4; q++) {
    for (int t = tid; t < 384; t += 256) {
      int jyL = t >> 5, rr = t & 31;
      const float* pp = sB + OFF_PHT + (q * 12 + jyL) * 8;
      float d = 0.f;
      #pragma unroll
      for (int j = 0; j < 8; j++) d = fmaf(sB[OFF_QT + j * 32 + rr], pp[j], d);
      sB[OFF_EA + jyL * 32 + ((rr & 15) << 1) + (rr >> 4)] = __expf(d);
    }
    __syncthreads();   // publish eA(q); drains V(q) DMA (for q>0)
    #pragma unroll 1
    for (int jyL = 0; jyL < 12; jyL++) {
      float2 eA = *(const float2*)(sB + OFF_EA + jyL * 32 + rl16 * 2);
      int cb = (q * 12 + jyL) * 48 + g * 3;     // global j of i=0
      int J0 = cb >> 6, J1 = (cb + 2) >> 6;
      int ib = 64 - (cb & 63);                  // i >= ib uses J1
      float e0 = sB[OFF_E + J0];
      float e1 = sB[OFF_E + J1];
      float a00 = eA.x * e0, a01 = eA.x * e1;
      float a10 = eA.y * e0, a11 = eA.y * e1;
      #pragma unroll
      for (int i = 0; i < 3; i++) {
        float4 vlo = sV4[(jyL * 48 + g * 3 + i) * 2];
        float4 vhi = sV4[(jyL * 48 + g * 3 + i) * 2 + 1];
        bool sel = (i < ib);
        float w0 = (sel ? a00 : a01) * eB[0][i];
        float w1 = (sel ? a10 : a11) * eB[1][i];
        acc0[0] = fmaf(w0, vlo.x, acc0[0]);  acc1[0] = fmaf(w1, vlo.x, acc1[0]);
        acc0[1] = fmaf(w0, vlo.y, acc0[1]);  acc1[1] = fmaf(w1, vlo.y, acc1[1]);
        acc0[2] = fmaf(w0, vlo.z, acc0[2]);  acc1[2] = fmaf(w1, vlo.z, acc1[2]);
        acc0[3] = fmaf(w0, vlo.w, acc0[3]);  acc1[3] = fmaf(w1, vlo.w, acc1[3]);
        acc0[4] = fmaf(w0, vhi.x, acc0[4]);  acc1[4] = fmaf(w1, vhi.x, acc1[4]);
        acc0[5] = fmaf(w0, vhi.y, acc0[5]);  acc1[5] = fmaf(w1, vhi.y, acc1[5]);
        acc0[6] = fmaf(w0, vhi.z, acc0[6]);  acc1[6] = fmaf(w1, vhi.z, acc1[6]);
        acc0[7] = fmaf(w0, vhi.w, acc0[7]);  acc1[7] = fmaf(w1, vhi.w, acc1[7]);
        acc0[8] += w0;                        acc1[8] += w1;
      }
    }
    if (q < 3) {
      __syncthreads();   // all waves done reading V(q)/eA(q)
      const char* src = (const char*)(V2 + (size_t)bh * (HW * 8) + (size_t)(q + 1) * 4608);
      for (int m = w; m < 18; m += 4)
        dma16(src + m * 1024 + lane * 16, (char*)(sB + OFF_V) + m * 1024);
    }
  }
  #pragma unroll
  for (int c = 0; c < 9; c++) {
    acc0[c] += __shfl_xor(acc0[c], 16, 64);
    acc0[c] += __shfl_xor(acc0[c], 32, 64);
    acc1[c] += __shfl_xor(acc1[c], 16, 64);
    acc1[c] += __shfl_xor(acc1[c], 32, 64);
  }
  if ((lane & 48) == 0) {   // lanes 0-15 hold the wave's group-sum
    #pragma unroll
    for (int c = 0; c < 9; c++) {
      sB[OFF_R + ((w * 2 + 0) * 16 + rl16) * 9 + c] = acc0[c];
      sB[OFF_R + ((w * 2 + 1) * 16 + rl16) * 9 + c] = acc1[c];
    }
  }
  __syncthreads();
  {
    int c = tid >> 5, r = tid & 31;   // 256 threads = 32 rows x 8 c
    int k = r >> 4, r16 = r & 15;
    float num = 0.f, z = 0.f;
    #pragma unroll
    for (int ww = 0; ww < 4; ww++) {
      num += sB[OFF_R + ((ww * 2 + k) * 16 + r16) * 9 + c];
      z   += sB[OFF_R + ((ww * 2 + k) * 16 + r16) * 9 + 8];
    }
    out[(b * 64 + h * 8 + c) * HW + S * 32 + r] = num / z;
  }
}

extern "C" void kernel_launch(void* const* d_in, const int* in_sizes, int n_in,
                              void* d_out, int out_size, void* d_ws, size_t ws_size,
                              hipStream_t stream) {
  const float* F    = (const float*)d_in[0];
  const float* Wqkv = (const float*)d_in[1];
  const float* Wq   = (const float*)d_in[2];
  const float* Bq   = (const float*)d_in[3];
  const float* Wk   = (const float*)d_in[4];
  const float* Bk   = (const float*)d_in[5];
  const float* PH   = (const float*)d_in[6];
  const float* PW   = (const float*)d_in[7];
  float* out = (float*)d_out;

  float* ws   = (float*)d_ws;
  float* QKV  = ws;                        // 884736 f
  float* V2   = QKV + 2 * HW * O192;       // 294912 f
  float* QD   = V2 + 2 * 8 * HW * 8;       // 9216 f   (~4.8 MB total)

  front_kernel<<<1280, 256, 0, stream>>>(F, Wqkv, Wq, Bq, Wk, Bk, QKV, V2, QD);
  attn_kernel <<<1152, 256, 0, stream>>>(QKV, V2, QD, PH, PW, out);
}